// Round 6
// baseline (230.978 us; speedup 1.0000x reference)
//
#include <hip/hip_runtime.h>
#include <hip/hip_bf16.h>

// KAN layer = GEMM: out[b,o] = sum_{i,k} T_k(tanh(x[b,i])) * W[o,i,k] + bias[o]
//   A (basis) : [4096, 8192] bf16 row-major (built in ws)
//   B (weights): [1024, 8192] bf16 row-major (converted in ws) -> gemm_bt
// Round-6: IN-BLOCK SPLIT-K. 512-thread blocks (8 waves): waves 0-3 do
// K-half 0, waves 4-7 K-half 1, same 128x128 output tile. Grid 256 = 1
// block/CU but 8 waves/CU (r2's proven TLP). Two-barrier single-buffer
// K-loop (r2-proven; explicit dbuf regressed twice: r4, r5). Wave tile
// 64x64 (4x4 of 16x16x32) = 1.5x less LDS-read traffic/FLOP than r2.
// Deterministic LDS reduction of the two K-halves; no atomics, ws = 80 MB.
#define MD 4096
#define ND 1024
#define KD 8192
#define IN_F 1024

typedef __bf16 bf16x8 __attribute__((ext_vector_type(8)));
typedef float f32x4 __attribute__((ext_vector_type(4)));

// ---------------- Prep: basis (fast tanh) + W convert, vectorized ----------
#define NT_BASIS (MD * IN_F / 4)   // 1048576 threads, 4 x-elems each
#define NT_CONV (ND * KD / 16)     // 524288 threads, 16 w-floats each

__device__ __forceinline__ float fast_tanh(float v) {
  // tanh(v) = 1 - 2/(e^{2v}+1); saturates correctly: e->inf => 1, e->0 => -1
  float e = __expf(2.0f * v);
  return 1.0f - 2.0f / (e + 1.0f);
}

__device__ __forceinline__ bf16x8 cheb8(float t) {
  float two_t = 2.0f * t;
  float T0 = 1.0f;
  float T1 = t;
  float T2 = two_t * T1 - T0;
  float T3 = two_t * T2 - T1;
  float T4 = two_t * T3 - T2;
  float T5 = two_t * T4 - T3;
  float T6 = two_t * T5 - T4;
  float T7 = two_t * T6 - T5;
  bf16x8 v;
  v[0] = (__bf16)T0; v[1] = (__bf16)T1; v[2] = (__bf16)T2; v[3] = (__bf16)T3;
  v[4] = (__bf16)T4; v[5] = (__bf16)T5; v[6] = (__bf16)T6; v[7] = (__bf16)T7;
  return v;
}

__global__ __launch_bounds__(256) void prep_kernel(
    const float* __restrict__ x, const float* __restrict__ w,
    __bf16* __restrict__ A, __bf16* __restrict__ B) {
  int i = blockIdx.x * blockDim.x + threadIdx.x;
  if (i < NT_BASIS) {
    float4 xv = *(const float4*)(x + (size_t)i * 4);
    __bf16* dst = A + (size_t)i * 32;  // 4 x-elems -> 64 B contiguous
    *(bf16x8*)(dst + 0)  = cheb8(fast_tanh(xv.x));
    *(bf16x8*)(dst + 8)  = cheb8(fast_tanh(xv.y));
    *(bf16x8*)(dst + 16) = cheb8(fast_tanh(xv.z));
    *(bf16x8*)(dst + 24) = cheb8(fast_tanh(xv.w));
  } else if (i < NT_BASIS + NT_CONV) {
    int j = i - NT_BASIS;
    const float4* p = (const float4*)(w + (size_t)j * 16);
    float4 a = p[0], b = p[1], c = p[2], d = p[3];
    bf16x8 v0, v1;
    v0[0] = (__bf16)a.x; v0[1] = (__bf16)a.y; v0[2] = (__bf16)a.z; v0[3] = (__bf16)a.w;
    v0[4] = (__bf16)b.x; v0[5] = (__bf16)b.y; v0[6] = (__bf16)b.z; v0[7] = (__bf16)b.w;
    v1[0] = (__bf16)c.x; v1[1] = (__bf16)c.y; v1[2] = (__bf16)c.z; v1[3] = (__bf16)c.w;
    v1[4] = (__bf16)d.x; v1[5] = (__bf16)d.y; v1[6] = (__bf16)d.z; v1[7] = (__bf16)d.w;
    *(bf16x8*)(B + (size_t)j * 16)     = v0;
    *(bf16x8*)(B + (size_t)j * 16 + 8) = v1;
  }
}

// ---------------- GEMM_BT + bias: in-block split-K ----------------
#define BM 128
#define BN 128
#define BK 64
#define KHALF (KD / 2)        // 4096 per K-group
#define KITERS (KHALF / BK)   // 64

__global__ __launch_bounds__(512, 2) void gemm_bias(
    const __bf16* __restrict__ A, const __bf16* __restrict__ B,
    const float* __restrict__ bias, float* __restrict__ C) {
  // per K-group single-buffered tiles: 2 x (16 KB A + 16 KB B) = 64 KB
  __shared__ __align__(16) __bf16 As[2][BM * BK];
  __shared__ __align__(16) __bf16 Bs[2][BN * BK];
  // reduction exchange: 256 threads x 64 floats, stride 68 for alignment+banks
  __shared__ __align__(16) float red[256 * 68];

  const int tid = threadIdx.x;
  const int kg = tid >> 8;    // K-group 0/1
  const int t = tid & 255;
  const int wave = t >> 6;    // 0..3 within group
  const int lane = tid & 63;
  const int n0 = blockIdx.x * BN;
  const int m0 = blockIdx.y * BM;
  const int wm = wave >> 1;   // 0..1
  const int wn = wave & 1;    // 0..1

  // ---- staging: global_load_lds 16B/lane; XOR swizzle (r2-proven, 0 confl).
  // Physical slot (row,pg) holds logical group pg^(row&7).
  const int ar = lane >> 3;                   // 0..7
  const int swz_col = ((lane & 7) ^ ar) * 8;  // swizzled 8-elem column group
  const __bf16* gA = A + (size_t)(m0 + wave * 32 + ar) * KD + kg * KHALF + swz_col;
  const __bf16* gB = B + (size_t)(n0 + wave * 32 + ar) * KD + kg * KHALF + swz_col;
  __bf16* lA = &As[kg][(wave * 32) * BK];
  __bf16* lB = &Bs[kg][(wave * 32) * BK];

  f32x4 acc[4][4];
#pragma unroll
  for (int i = 0; i < 4; i++)
#pragma unroll
    for (int j = 0; j < 4; j++) acc[i][j] = (f32x4){0.f, 0.f, 0.f, 0.f};

  // ---- fragment coords (16x16x32: m=lane&15, k=(lane>>4)*8+j)
  const int fr = lane & 15;
  const int fr7 = fr & 7;
  const int qk = lane >> 4;  // 0..3

  for (int it = 0; it < KITERS; it++) {
    const int g = it * BK;
    // stage this group's A/B tiles (4 instr each, 8 rows/instr)
#pragma unroll
    for (int j = 0; j < 4; j++)
      __builtin_amdgcn_global_load_lds(
          (const __attribute__((address_space(1))) void*)(gA + g + (size_t)j * 8 * KD),
          (__attribute__((address_space(3))) void*)(lA + j * 8 * BK), 16, 0, 0);
#pragma unroll
    for (int j = 0; j < 4; j++)
      __builtin_amdgcn_global_load_lds(
          (const __attribute__((address_space(1))) void*)(gB + g + (size_t)j * 8 * KD),
          (__attribute__((address_space(3))) void*)(lB + j * 8 * BK), 16, 0, 0);
    __syncthreads();  // drain vmcnt; tiles visible to all

    // compute on this group's buffers; wave tile 64x64 = 4x4 frags
#pragma unroll
    for (int s = 0; s < 2; s++) {
      const int pa = ((s * 4 + qk) ^ fr7) * 8;  // swizzled physical group
      bf16x8 af[4], bfr[4];
#pragma unroll
      for (int mi = 0; mi < 4; mi++)
        af[mi] = *(const bf16x8*)&As[kg][(wm * 64 + mi * 16 + fr) * BK + pa];
#pragma unroll
      for (int ni = 0; ni < 4; ni++)
        bfr[ni] = *(const bf16x8*)&Bs[kg][(wn * 64 + ni * 16 + fr) * BK + pa];
#pragma unroll
      for (int mi = 0; mi < 4; mi++)
#pragma unroll
        for (int ni = 0; ni < 4; ni++)
          acc[mi][ni] = __builtin_amdgcn_mfma_f32_16x16x32_bf16(
              af[mi], bfr[ni], acc[mi][ni], 0, 0, 0);
    }
    __syncthreads();  // all waves done reading before next stage overwrites
  }

  // ---- reduce the two K-halves via LDS, then epilogue by group 0
  if (kg == 1) {
    float* dst = &red[t * 68];
#pragma unroll
    for (int mi = 0; mi < 4; mi++)
#pragma unroll
      for (int ni = 0; ni < 4; ni++)
        *(f32x4*)(dst + (mi * 4 + ni) * 4) = acc[mi][ni];
  }
  __syncthreads();
  if (kg == 0) {
    const float* src = &red[t * 68];
    const int row0 = m0 + wm * 64 + (lane >> 4) * 4;
    const int col0 = n0 + wn * 64;
#pragma unroll
    for (int ni = 0; ni < 4; ni++) {
      int col = col0 + ni * 16 + (lane & 15);
      float bv = bias[col];
#pragma unroll
      for (int mi = 0; mi < 4; mi++) {
        f32x4 part = *(const f32x4*)(src + (mi * 4 + ni) * 4);
        int row = row0 + mi * 16;
#pragma unroll
        for (int r = 0; r < 4; r++)
          C[(size_t)(row + r) * ND + col] = acc[mi][ni][r] + part[r] + bv;
      }
    }
  }
}

extern "C" void kernel_launch(void* const* d_in, const int* in_sizes, int n_in,
                              void* d_out, int out_size, void* d_ws, size_t ws_size,
                              hipStream_t stream) {
  const float* x = (const float*)d_in[0];     // [4096,1024]
  const float* w = (const float*)d_in[1];     // [1024,1024,8]
  const float* bias = (const float*)d_in[2];  // [1024]
  float* out = (float*)d_out;                 // [4096,1024]

  __bf16* Abf = (__bf16*)d_ws;                                 // 64 MB
  __bf16* Bbf = (__bf16*)((char*)d_ws + (size_t)MD * KD * 2);  // 16 MB

  {
    int n = NT_BASIS + NT_CONV;  // 1572864
    prep_kernel<<<(n + 255) / 256, 256, 0, stream>>>(x, w, Abf, Bbf);
  }
  {
    dim3 grid(ND / BN, MD / BM);  // (8, 32) = 256 blocks, 512 thr = 8 waves/CU
    gemm_bias<<<grid, 512, 0, stream>>>(Abf, Bbf, bias, out);
  }
}

// Round 7
// 205.324 us; speedup vs baseline: 1.1249x; 1.1249x over previous
//
#include <hip/hip_runtime.h>
#include <hip/hip_bf16.h>

// KAN layer = GEMM: out[b,o] = sum_{i,k} T_k(tanh(x[b,i])) * W[o,i,k] + bias[o]
//   A (basis) : [4096, 8192] bf16 row-major (built in ws)
//   B (weights): [1024, 8192] bf16 row-major (converted in ws) -> gemm_bt
// Round-7: CROSS-BLOCK SPLIT-K. Laws learned r2-r6:
//   * >=2 INDEPENDENT blocks/CU (barrier drain of one block hides under the
//     other's compute; r4/r6's 1-block/CU barrier-coupling cost ~2x).
//   * single-buffer two-barrier K-loop (explicit dbuf regressed twice).
//   * LDS traffic/MAC = 2(1/wtM+1/wtN): only wave-tile size matters.
// Design: grid (8,32,2) = 512 blocks (2/CU), each 256 thr = 4 waves 2x2 of
// 64x64 wave tiles on a 128x128 C-tile, K-half per blockIdx.z. Partials
// combined via fp32 atomicAdd into memset-zeroed C (2 contributors/elem,
// bias folded into kg=0). vs r2: VMEM/MAC and LDS/MAC both / 1.5.
#define MD 4096
#define ND 1024
#define KD 8192
#define IN_F 1024

typedef __bf16 bf16x8 __attribute__((ext_vector_type(8)));
typedef float f32x4 __attribute__((ext_vector_type(4)));

// ---------------- Prep: basis (fast tanh) + W convert, vectorized ----------
#define NT_BASIS (MD * IN_F / 4)   // 1048576 threads, 4 x-elems each
#define NT_CONV (ND * KD / 16)     // 524288 threads, 16 w-floats each

__device__ __forceinline__ float fast_tanh(float v) {
  float e = __expf(2.0f * v);
  return 1.0f - 2.0f / (e + 1.0f);
}

__device__ __forceinline__ bf16x8 cheb8(float t) {
  float two_t = 2.0f * t;
  float T0 = 1.0f;
  float T1 = t;
  float T2 = two_t * T1 - T0;
  float T3 = two_t * T2 - T1;
  float T4 = two_t * T3 - T2;
  float T5 = two_t * T4 - T3;
  float T6 = two_t * T5 - T4;
  float T7 = two_t * T6 - T5;
  bf16x8 v;
  v[0] = (__bf16)T0; v[1] = (__bf16)T1; v[2] = (__bf16)T2; v[3] = (__bf16)T3;
  v[4] = (__bf16)T4; v[5] = (__bf16)T5; v[6] = (__bf16)T6; v[7] = (__bf16)T7;
  return v;
}

__global__ __launch_bounds__(256) void prep_kernel(
    const float* __restrict__ x, const float* __restrict__ w,
    __bf16* __restrict__ A, __bf16* __restrict__ B) {
  int i = blockIdx.x * blockDim.x + threadIdx.x;
  if (i < NT_BASIS) {
    float4 xv = *(const float4*)(x + (size_t)i * 4);
    __bf16* dst = A + (size_t)i * 32;
    *(bf16x8*)(dst + 0)  = cheb8(fast_tanh(xv.x));
    *(bf16x8*)(dst + 8)  = cheb8(fast_tanh(xv.y));
    *(bf16x8*)(dst + 16) = cheb8(fast_tanh(xv.z));
    *(bf16x8*)(dst + 24) = cheb8(fast_tanh(xv.w));
  } else if (i < NT_BASIS + NT_CONV) {
    int j = i - NT_BASIS;
    const float4* p = (const float4*)(w + (size_t)j * 16);
    float4 a = p[0], b = p[1], c = p[2], d = p[3];
    bf16x8 v0, v1;
    v0[0] = (__bf16)a.x; v0[1] = (__bf16)a.y; v0[2] = (__bf16)a.z; v0[3] = (__bf16)a.w;
    v0[4] = (__bf16)b.x; v0[5] = (__bf16)b.y; v0[6] = (__bf16)b.z; v0[7] = (__bf16)b.w;
    v1[0] = (__bf16)c.x; v1[1] = (__bf16)c.y; v1[2] = (__bf16)c.z; v1[3] = (__bf16)c.w;
    v1[4] = (__bf16)d.x; v1[5] = (__bf16)d.y; v1[6] = (__bf16)d.z; v1[7] = (__bf16)d.w;
    *(bf16x8*)(B + (size_t)j * 16)     = v0;
    *(bf16x8*)(B + (size_t)j * 16 + 8) = v1;
  }
}

// ---------------- GEMM_BT split-K: 128x128 tile, 64x64 wave tiles ----------
#define BM 128
#define BN 128
#define BK 64
#define KHALF (KD / 2)       // 4096
#define KITERS (KHALF / BK)  // 64

__global__ __launch_bounds__(256, 2) void gemm_splitk(
    const __bf16* __restrict__ A, const __bf16* __restrict__ B,
    const float* __restrict__ bias, float* __restrict__ C) {
  // single-buffer tiles: 16 KB A + 16 KB B = 32 KB -> 2 blocks/CU co-resident
  __shared__ __align__(16) __bf16 As[BM * BK];
  __shared__ __align__(16) __bf16 Bs[BN * BK];

  const int tid = threadIdx.x;
  const int wave = tid >> 6;
  const int lane = tid & 63;
  const int n0 = blockIdx.x * BN;
  const int m0 = blockIdx.y * BM;
  const int kg = blockIdx.z;            // K-half 0/1
  const size_t k0 = (size_t)kg * KHALF;
  const int wm = wave >> 1;  // 0..1
  const int wn = wave & 1;   // 0..1

  // ---- staging: global_load_lds 16B/lane; XOR swizzle (0 conflicts, proven).
  // Physical slot (row,pg) holds logical group pg^(row&7).
  const int ar = lane >> 3;
  const int swz_col = ((lane & 7) ^ ar) * 8;
  const __bf16* gA = A + (size_t)(m0 + wave * 32 + ar) * KD + k0 + swz_col;
  const __bf16* gB = B + (size_t)(n0 + wave * 32 + ar) * KD + k0 + swz_col;
  __bf16* lA = As + (wave * 32) * BK;  // each wave stages 32 rows (4 instr)
  __bf16* lB = Bs + (wave * 32) * BK;

  f32x4 acc[4][4];
#pragma unroll
  for (int i = 0; i < 4; i++)
#pragma unroll
    for (int j = 0; j < 4; j++) acc[i][j] = (f32x4){0.f, 0.f, 0.f, 0.f};

  // ---- fragment coords (16x16x32: m=lane&15, k=(lane>>4)*8+j)
  const int fr = lane & 15;
  const int fr7 = fr & 7;
  const int qk = lane >> 4;

#pragma unroll 2
  for (int it = 0; it < KITERS; it++) {
    const int g = it * BK;
#pragma unroll
    for (int j = 0; j < 4; j++)
      __builtin_amdgcn_global_load_lds(
          (const __attribute__((address_space(1))) void*)(gA + g + (size_t)j * 8 * KD),
          (__attribute__((address_space(3))) void*)(lA + j * 8 * BK), 16, 0, 0);
#pragma unroll
    for (int j = 0; j < 4; j++)
      __builtin_amdgcn_global_load_lds(
          (const __attribute__((address_space(1))) void*)(gB + g + (size_t)j * 8 * KD),
          (__attribute__((address_space(3))) void*)(lB + j * 8 * BK), 16, 0, 0);
    __syncthreads();  // drain vmcnt; tiles visible

    // wave tile 64x64 = 4x4 of 16x16x32
#pragma unroll
    for (int s = 0; s < 2; s++) {
      const int pa = ((s * 4 + qk) ^ fr7) * 8;
      bf16x8 af[4], bfr[4];
#pragma unroll
      for (int mi = 0; mi < 4; mi++)
        af[mi] = *(const bf16x8*)&As[(wm * 64 + mi * 16 + fr) * BK + pa];
#pragma unroll
      for (int ni = 0; ni < 4; ni++)
        bfr[ni] = *(const bf16x8*)&Bs[(wn * 64 + ni * 16 + fr) * BK + pa];
#pragma unroll
      for (int mi = 0; mi < 4; mi++)
#pragma unroll
        for (int ni = 0; ni < 4; ni++)
          acc[mi][ni] = __builtin_amdgcn_mfma_f32_16x16x32_bf16(
              af[mi], bfr[ni], acc[mi][ni], 0, 0, 0);
    }
    __syncthreads();  // all waves done reading before next stage
  }

  // ---- epilogue: atomic accumulate into zeroed C; bias folded into kg==0.
  // C/D layout: col=lane&15, row=(lane>>4)*4+r
  const int row0 = m0 + wm * 64 + qk * 4;
  const int col0 = n0 + wn * 64;
#pragma unroll
  for (int ni = 0; ni < 4; ni++) {
    int col = col0 + ni * 16 + fr;
    float bv = (kg == 0) ? bias[col] : 0.0f;
#pragma unroll
    for (int mi = 0; mi < 4; mi++) {
      int row = row0 + mi * 16;
#pragma unroll
      for (int r = 0; r < 4; r++)
        atomicAdd(&C[(size_t)(row + r) * ND + col], acc[mi][ni][r] + bv);
    }
  }
}

extern "C" void kernel_launch(void* const* d_in, const int* in_sizes, int n_in,
                              void* d_out, int out_size, void* d_ws, size_t ws_size,
                              hipStream_t stream) {
  const float* x = (const float*)d_in[0];     // [4096,1024]
  const float* w = (const float*)d_in[1];     // [1024,1024,8]
  const float* bias = (const float*)d_in[2];  // [1024]
  float* out = (float*)d_out;                 // [4096,1024]

  __bf16* Abf = (__bf16*)d_ws;                                 // 64 MB
  __bf16* Bbf = (__bf16*)((char*)d_ws + (size_t)MD * KD * 2);  // 16 MB

  // C accumulated atomically -> zero it (graph-capture-safe memset node)
  hipMemsetAsync(out, 0, (size_t)out_size * sizeof(float), stream);
  {
    int n = NT_BASIS + NT_CONV;
    prep_kernel<<<(n + 255) / 256, 256, 0, stream>>>(x, w, Abf, Bbf);
  }
  {
    dim3 grid(ND / BN, MD / BM, 2);  // (8, 32, 2) = 512 blocks -> 2/CU
    gemm_splitk<<<grid, 256, 0, stream>>>(Abf, Bbf, bias, out);
  }
}